// Round 9
// baseline (555.400 us; speedup 1.0000x reference)
//
#include <hip/hip_runtime.h>

#define NN 50000
#define NE 1600000
#define DD 128
#define NL 4
#define NG 512
#define NBUK 196    // dst buckets of 256 nodes: ceil(50000/256)
#define NBLK 196    // edge blocks: ceil(NE/8192)
#define EPB 8192    // edges per block in bucket passes
#define HN (NBUK * NBLK)  // 38416
#define HT 151      // ceil(HN/256)

typedef __attribute__((ext_vector_type(8))) short short8;
typedef __attribute__((ext_vector_type(4))) float floatx4;

__device__ __forceinline__ unsigned short f2bf(float f) {
    unsigned int u = __float_as_uint(f);
    u += 0x7fffu + ((u >> 16) & 1u);
    return (unsigned short)(u >> 16);
}
__device__ __forceinline__ float bf2f(unsigned short u) {
    return __uint_as_float(((unsigned int)u) << 16);
}

// ---------- fp32 -> bf16 convert (layer-0 input) ----------
__global__ __launch_bounds__(256) void cvt_kernel(const float* __restrict__ x,
                                                  unsigned short* __restrict__ xbf) {
    int idx = blockIdx.x * 256 + threadIdx.x;  // one float4 per thread
    float4 f = ((const float4*)x)[idx];
    ushort4 o;
    o.x = f2bf(f.x); o.y = f2bf(f.y); o.z = f2bf(f.z); o.w = f2bf(f.w);
    ((ushort4*)xbf)[idx] = o;
}

// ---------- CSR build: LDS-only counting sort (ZERO global atomics) ----------
// R6/R7 counters proved global atomic RMWs execute memory-side on gfx950
// (~35 B write-through + serialized round trip each, scope hints ignored).

// Pass 1: per-(block, bucket) histogram, bucket = dst>>8
__global__ __launch_bounds__(512) void bhist_kernel(const int* __restrict__ dst,
                                                    int* __restrict__ hist) {
    __shared__ int h[NBUK];
    int tid = threadIdx.x;
    for (int i = tid; i < NBUK; i += 512) h[i] = 0;
    __syncthreads();
    int base = blockIdx.x * EPB;
#pragma unroll
    for (int it = 0; it < EPB / 512; it++) {
        int e = base + it * 512 + tid;
        if (e < NE) atomicAdd(&h[dst[e] >> 8], 1);
    }
    __syncthreads();
    for (int i = tid; i < NBUK; i += 512) hist[i * NBLK + blockIdx.x] = h[i];
}

// Pass 2a/2b/2c: exclusive scan of hist[HN] (bucket-major) -> bkoff[HN]
__global__ __launch_bounds__(256) void sum_tiles_kernel(const int* __restrict__ in,
                                                        int* __restrict__ tsum, int n) {
    int i = blockIdx.x * 256 + threadIdx.x;
    __shared__ int s[256];
    s[threadIdx.x] = (i < n) ? in[i] : 0;
    __syncthreads();
    for (int off = 128; off > 0; off >>= 1) {
        if (threadIdx.x < off) s[threadIdx.x] += s[threadIdx.x + off];
        __syncthreads();
    }
    if (threadIdx.x == 0) tsum[blockIdx.x] = s[0];
}

__global__ __launch_bounds__(256) void scan_tiles_kernel(const int* __restrict__ tsum,
                                                         int* __restrict__ toff, int ntiles) {
    int t = threadIdx.x;
    __shared__ int s[256];
    int v = (t < ntiles) ? tsum[t] : 0;
    s[t] = v;
    __syncthreads();
    for (int off = 1; off < 256; off <<= 1) {
        int u = (t >= off) ? s[t - off] : 0;
        __syncthreads();
        s[t] += u;
        __syncthreads();
    }
    if (t < ntiles) toff[t] = s[t] - v;
}

__global__ __launch_bounds__(256) void scan_out_kernel(const int* __restrict__ in,
                                                       const int* __restrict__ toff,
                                                       int* __restrict__ out, int n) {
    int i = blockIdx.x * 256 + threadIdx.x;
    int t = threadIdx.x;
    int v = (i < n) ? in[i] : 0;
    __shared__ int s[256];
    s[t] = v;
    __syncthreads();
    for (int off = 1; off < 256; off <<= 1) {
        int u = (t >= off) ? s[t - off] : 0;
        __syncthreads();
        s[t] += u;
        __syncthreads();
    }
    if (i < n) out[i] = toff[blockIdx.x] + s[t] - v;
}

// Pass 3: scatter edges into bucket-sorted ebuf, PACKED: (src<<8)|(dst&255).
// src < 50000 < 2^16 so the pack fits 24 bits — halves ebuf traffic vs int2.
__global__ __launch_bounds__(512) void bscatter_kernel(const int* __restrict__ src,
                                                       const int* __restrict__ dst,
                                                       const int* __restrict__ bkoff,
                                                       int* __restrict__ ebuf) {
    __shared__ int h[NBUK];
    int tid = threadIdx.x;
    for (int i = tid; i < NBUK; i += 512) h[i] = 0;
    __syncthreads();
    int base = blockIdx.x * EPB;
#pragma unroll
    for (int it = 0; it < EPB / 512; it++) {
        int e = base + it * 512 + tid;
        if (e < NE) {
            int d = dst[e];
            int bu = d >> 8;
            int p = atomicAdd(&h[bu], 1);
            ebuf[bkoff[bu * NBLK + blockIdx.x] + p] = (src[e] << 8) | (d & 255);
        }
    }
}

// Pass 4: one block per bucket (256 nodes): LDS histogram over dst&255 -> LDS scan
// -> rowptr for this bucket's nodes + scatter src into final CSR col.
__global__ __launch_bounds__(256) void bucket_csr_kernel(const int* __restrict__ ebuf,
                                                         const int* __restrict__ bkoff,
                                                         int* __restrict__ rowptr,
                                                         int* __restrict__ col) {
    __shared__ int cnt[256], exc[256], c2[256];
    int b = blockIdx.x, tid = threadIdx.x;
    int segstart = bkoff[b * NBLK];
    int segend = (b < NBUK - 1) ? bkoff[(b + 1) * NBLK] : NE;
    cnt[tid] = 0;
    c2[tid] = 0;
    __syncthreads();
    for (int i = segstart + tid; i < segend; i += 256)
        atomicAdd(&cnt[ebuf[i] & 255], 1);
    __syncthreads();
    int v = cnt[tid];
    exc[tid] = v;
    __syncthreads();
    for (int off = 1; off < 256; off <<= 1) {
        int u = (tid >= off) ? exc[tid - off] : 0;
        __syncthreads();
        exc[tid] += u;
        __syncthreads();
    }
    int excl = exc[tid] - v;  // exclusive prefix
    exc[tid] = excl;          // own-slot rewrite; others read only after barrier
    int node = (b << 8) + tid;
    if (node <= NN) rowptr[node] = segstart + excl;
    __syncthreads();
    for (int i = segstart + tid; i < segend; i += 256) {
        int ev = ebuf[i];
        int low = ev & 255;
        int p = atomicAdd(&c2[low], 1);
        col[segstart + exc[low] + p] = ((unsigned)ev) >> 8;
    }
}

// ---------- weight prep: fp32 [l][k][n] -> bf16 transposed [l][n][k] ----------
__global__ __launch_bounds__(256) void prep_kernel(const float* __restrict__ Ws1,
                                                   const float* __restrict__ Ws2,
                                                   unsigned short* __restrict__ W1T,
                                                   unsigned short* __restrict__ W2T) {
    int idx = blockIdx.x * 256 + threadIdx.x;  // [0, NL*DD*DD)
    int l = idx >> 14;
    int rem = idx & 16383;
    int k = rem >> 7;
    int n = rem & 127;
    int o = (l << 14) + (n << 7) + k;
    W1T[o] = f2bf(Ws1[idx]);
    W2T[o] = f2bf(Ws2[idx]);
}

// ---------- aggregation: hpre[i] = x[i] + sum_{j in N(i)} x[j], bf16 in/out ----------
// Standalone (NOT fused — R5: fusing cost 2.4x fetch rate via occupancy).
// 16 lanes/node, uint4 (8 bf16) per lane; fp32 accum; x8 edge unroll.
__global__ __launch_bounds__(256) void agg_kernel(const unsigned short* __restrict__ xbf,
                                                  const int* __restrict__ rowptr,
                                                  const int* __restrict__ col,
                                                  unsigned short* __restrict__ hpre) {
    int g = threadIdx.x >> 4;   // 16 node-groups per block
    int lane = threadIdx.x & 15;
    int node = blockIdx.x * 16 + g;  // NN = 3125*16 exactly
    const uint4* base = (const uint4*)xbf;
    float a[8];
    {
        uint4 v = base[node * 16 + lane];
        a[0] = __uint_as_float(v.x << 16); a[1] = __uint_as_float(v.x & 0xFFFF0000u);
        a[2] = __uint_as_float(v.y << 16); a[3] = __uint_as_float(v.y & 0xFFFF0000u);
        a[4] = __uint_as_float(v.z << 16); a[5] = __uint_as_float(v.z & 0xFFFF0000u);
        a[6] = __uint_as_float(v.w << 16); a[7] = __uint_as_float(v.w & 0xFFFF0000u);
    }
    int s = rowptr[node], e = rowptr[node + 1];
    int i = s;
    for (; i + 8 <= e; i += 8) {
        uint4 v0 = base[col[i] * 16 + lane];
        uint4 v1 = base[col[i + 1] * 16 + lane];
        uint4 v2 = base[col[i + 2] * 16 + lane];
        uint4 v3 = base[col[i + 3] * 16 + lane];
        uint4 v4 = base[col[i + 4] * 16 + lane];
        uint4 v5 = base[col[i + 5] * 16 + lane];
        uint4 v6 = base[col[i + 6] * 16 + lane];
        uint4 v7 = base[col[i + 7] * 16 + lane];
#define ACC(V)                                                            \
        a[0] += __uint_as_float(V.x << 16); a[1] += __uint_as_float(V.x & 0xFFFF0000u); \
        a[2] += __uint_as_float(V.y << 16); a[3] += __uint_as_float(V.y & 0xFFFF0000u); \
        a[4] += __uint_as_float(V.z << 16); a[5] += __uint_as_float(V.z & 0xFFFF0000u); \
        a[6] += __uint_as_float(V.w << 16); a[7] += __uint_as_float(V.w & 0xFFFF0000u)
        ACC(v0); ACC(v1); ACC(v2); ACC(v3); ACC(v4); ACC(v5); ACC(v6); ACC(v7);
    }
    for (; i < e; i++) {
        uint4 v = base[col[i] * 16 + lane];
        ACC(v);
    }
#undef ACC
    uint4 o;
    o.x = (unsigned int)f2bf(a[0]) | ((unsigned int)f2bf(a[1]) << 16);
    o.y = (unsigned int)f2bf(a[2]) | ((unsigned int)f2bf(a[3]) << 16);
    o.z = (unsigned int)f2bf(a[4]) | ((unsigned int)f2bf(a[5]) << 16);
    o.w = (unsigned int)f2bf(a[6]) | ((unsigned int)f2bf(a[7]) << 16);
    ((uint4*)hpre)[node * 16 + lane] = o;
}

// ---------- MLP as two barrier-free GEMMs ----------
// R8 ledger: fused mlp ~50 us/layer for 3.3 GFLOP + 38 MB — 5x off roofline,
// grid-starved at 782 blocks (12 waves/CU) + 2 barriers + full-W per wave.
// Split: 64 rows x 64 cols per block -> 1564 blocks, no LDS, no barriers,
// half-W per block. H round-trips via global (+25.6 MB/layer, ~5 us).
// h_kernel: H = relu(A@W1 + b1)
__global__ __launch_bounds__(256) void h_kernel(const unsigned short* __restrict__ A,
                                                const unsigned short* __restrict__ W1T,
                                                const float* __restrict__ b1,
                                                unsigned short* __restrict__ H) {
    int bx = blockIdx.x;
    int m = bx >> 1, nh = bx & 1;
    int tid = threadIdx.x;
    int w = tid >> 6;
    int lane = tid & 63;
    int quad = lane >> 4;
    int li = lane & 15;
    int rowb = m * 64 + 16 * w;
    int arow = rowb + li;
    bool valid = arow < NN;
    const unsigned short* arp = A + (size_t)arow * DD;

    floatx4 acc[4];
#pragma unroll
    for (int tn = 0; tn < 4; tn++) acc[tn] = (floatx4){0.f, 0.f, 0.f, 0.f};
#pragma unroll
    for (int kk = 0; kk < 4; kk++) {
        int k0 = kk * 32 + quad * 8;
        short8 af = valid ? *(const short8*)(arp + k0) : (short8){0, 0, 0, 0, 0, 0, 0, 0};
#pragma unroll
        for (int tn = 0; tn < 4; tn++) {
            int nt = nh * 4 + tn;
            short8 bf = *(const short8*)(W1T + ((nt * 16 + li) << 7) + k0);
            acc[tn] = __builtin_amdgcn_mfma_f32_16x16x32_bf16(af, bf, acc[tn], 0, 0, 0);
        }
    }
#pragma unroll
    for (int tn = 0; tn < 4; tn++) {
        int nt = nh * 4 + tn;
        float bias = b1[nt * 16 + li];
#pragma unroll
        for (int r = 0; r < 4; r++) {
            int grow = rowb + quad * 4 + r;
            if (grow < NN) {
                float v = fmaxf(acc[tn][r] + bias, 0.f);
                H[(size_t)grow * DD + nt * 16 + li] = f2bf(v);
            }
        }
    }
}

// o_kernel: out = H@W2 + b2
__global__ __launch_bounds__(256) void o_kernel(const unsigned short* __restrict__ H,
                                                const unsigned short* __restrict__ W2T,
                                                const float* __restrict__ b2,
                                                unsigned short* __restrict__ out) {
    int bx = blockIdx.x;
    int m = bx >> 1, nh = bx & 1;
    int tid = threadIdx.x;
    int w = tid >> 6;
    int lane = tid & 63;
    int quad = lane >> 4;
    int li = lane & 15;
    int rowb = m * 64 + 16 * w;
    int arow = rowb + li;
    bool valid = arow < NN;
    const unsigned short* arp = H + (size_t)arow * DD;

    floatx4 acc[4];
#pragma unroll
    for (int tn = 0; tn < 4; tn++) acc[tn] = (floatx4){0.f, 0.f, 0.f, 0.f};
#pragma unroll
    for (int kk = 0; kk < 4; kk++) {
        int k0 = kk * 32 + quad * 8;
        short8 af = valid ? *(const short8*)(arp + k0) : (short8){0, 0, 0, 0, 0, 0, 0, 0};
#pragma unroll
        for (int tn = 0; tn < 4; tn++) {
            int nt = nh * 4 + tn;
            short8 bf = *(const short8*)(W2T + ((nt * 16 + li) << 7) + k0);
            acc[tn] = __builtin_amdgcn_mfma_f32_16x16x32_bf16(af, bf, acc[tn], 0, 0, 0);
        }
    }
#pragma unroll
    for (int tn = 0; tn < 4; tn++) {
        int nt = nh * 4 + tn;
        float bias = b2[nt * 16 + li];
#pragma unroll
        for (int r = 0; r < 4; r++) {
            int grow = rowb + quad * 4 + r;
            if (grow < NN)
                out[(size_t)grow * DD + nt * 16 + li] = f2bf(acc[tn][r] + bias);
        }
    }
}

// ---------- global add pool: batch sorted -> per-graph contiguous range ----------
__global__ __launch_bounds__(128) void pool_kernel(const unsigned short* __restrict__ x,
                                                   const int* __restrict__ batch,
                                                   float* __restrict__ out) {
    int g = blockIdx.x;
    int lo = 0, hi = NN;
    while (lo < hi) { int mid = (lo + hi) >> 1; if (batch[mid] < g) lo = mid + 1; else hi = mid; }
    int s = lo;
    hi = NN;
    while (lo < hi) { int mid = (lo + hi) >> 1; if (batch[mid] < g + 1) lo = mid + 1; else hi = mid; }
    int e = lo;
    int d = threadIdx.x;
    float acc = 0.f;
    for (int i = s; i < e; i++) acc += bf2f(x[(size_t)i * DD + d]);
    out[g * DD + d] = acc;
}

extern "C" void kernel_launch(void* const* d_in, const int* in_sizes, int n_in,
                              void* d_out, int out_size, void* d_ws, size_t ws_size,
                              hipStream_t stream) {
    const float* x0 = (const float*)d_in[0];
    const int* edge = (const int*)d_in[1];
    const int* batch = (const int*)d_in[2];
    const float* Ws1 = (const float*)d_in[3];
    const float* bs1 = (const float*)d_in[4];
    const float* Ws2 = (const float*)d_in[5];
    const float* bs2 = (const float*)d_in[6];
    float* out = (float*)d_out;
    const int* src = edge;
    const int* dst = edge + NE;

    char* ws = (char*)d_ws;
    size_t off = 0;
    auto alloc = [&](size_t bytes) {
        void* p = ws + off;
        off += (bytes + 255) & ~(size_t)255;
        return p;
    };
    unsigned short* x0bf = (unsigned short*)alloc((size_t)NN * DD * 2);
    unsigned short* xA = (unsigned short*)alloc((size_t)NN * DD * 2);
    unsigned short* xB = (unsigned short*)alloc((size_t)NN * DD * 2);
    unsigned short* hpre = (unsigned short*)alloc((size_t)NN * DD * 2);
    unsigned short* Hbuf = (unsigned short*)alloc((size_t)NN * DD * 2);
    int* col = (int*)alloc((size_t)NE * 4);
    int* ebuf = (int*)alloc((size_t)NE * 4);
    int* hist = (int*)alloc((size_t)HN * 4);
    int* bkoff = (int*)alloc((size_t)HN * 4);
    int* tsum = (int*)alloc((size_t)HT * 4);
    int* toff = (int*)alloc((size_t)HT * 4);
    int* rowptr = (int*)alloc((size_t)(NN + 1) * 4);
    unsigned short* W1T = (unsigned short*)alloc((size_t)NL * DD * DD * 2);
    unsigned short* W2T = (unsigned short*)alloc((size_t)NL * DD * DD * 2);

    cvt_kernel<<<(NN * DD / 4) / 256, 256, 0, stream>>>(x0, x0bf);
    bhist_kernel<<<NBLK, 512, 0, stream>>>(dst, hist);
    sum_tiles_kernel<<<HT, 256, 0, stream>>>(hist, tsum, HN);
    scan_tiles_kernel<<<1, 256, 0, stream>>>(tsum, toff, HT);
    scan_out_kernel<<<HT, 256, 0, stream>>>(hist, toff, bkoff, HN);
    bscatter_kernel<<<NBLK, 512, 0, stream>>>(src, dst, bkoff, ebuf);
    bucket_csr_kernel<<<NBUK, 256, 0, stream>>>(ebuf, bkoff, rowptr, col);
    prep_kernel<<<(NL * DD * DD) / 256, 256, 0, stream>>>(Ws1, Ws2, W1T, W2T);

    const unsigned short* xin = x0bf;
    unsigned short* bufs[2] = {xA, xB};
    const int gemm_grid = ((NN + 63) / 64) * 2;  // 1564
    for (int l = 0; l < NL; l++) {
        agg_kernel<<<NN / 16, 256, 0, stream>>>(xin, rowptr, col, hpre);
        unsigned short* xout = bufs[l & 1];
        h_kernel<<<gemm_grid, 256, 0, stream>>>(hpre, W1T + l * DD * DD, bs1 + l * DD, Hbuf);
        o_kernel<<<gemm_grid, 256, 0, stream>>>(Hbuf, W2T + l * DD * DD, bs2 + l * DD, xout);
        xin = xout;
    }
    pool_kernel<<<NG, 128, 0, stream>>>(xin, batch, out);
}

// Round 11
// 494.704 us; speedup vs baseline: 1.1227x; 1.1227x over previous
//
#include <hip/hip_runtime.h>

#define NN 50000
#define NE 1600000
#define DD 128
#define NL 4
#define NG 512
#define NBUK 196    // dst buckets of 256 nodes: ceil(50000/256)
#define NBLK 196    // edge blocks: ceil(NE/8192)
#define EPB 8192    // edges per block in bucket passes
#define HN (NBUK * NBLK)  // 38416
#define HT 151      // ceil(HN/256)

typedef __attribute__((ext_vector_type(8))) short short8;
typedef __attribute__((ext_vector_type(4))) float floatx4;

__device__ __forceinline__ unsigned short f2bf(float f) {
    unsigned int u = __float_as_uint(f);
    u += 0x7fffu + ((u >> 16) & 1u);
    return (unsigned short)(u >> 16);
}
__device__ __forceinline__ float bf2f(unsigned short u) {
    return __uint_as_float(((unsigned int)u) << 16);
}

// ---------- fp32 -> bf16 convert (layer-0 input) ----------
__global__ __launch_bounds__(256) void cvt_kernel(const float* __restrict__ x,
                                                  unsigned short* __restrict__ xbf) {
    int idx = blockIdx.x * 256 + threadIdx.x;  // one float4 per thread
    float4 f = ((const float4*)x)[idx];
    ushort4 o;
    o.x = f2bf(f.x); o.y = f2bf(f.y); o.z = f2bf(f.z); o.w = f2bf(f.w);
    ((ushort4*)xbf)[idx] = o;
}

// ---------- CSR build: LDS-only counting sort (ZERO global atomics) ----------
// R6/R7: global atomic RMWs execute memory-side on gfx950 (~35 B write-through
// + serialized round trip each, scope hints ignored). Bucket sort, LDS atomics.

// Pass 1: per-(block, bucket) histogram, bucket = dst>>8
__global__ __launch_bounds__(512) void bhist_kernel(const int* __restrict__ dst,
                                                    int* __restrict__ hist) {
    __shared__ int h[NBUK];
    int tid = threadIdx.x;
    for (int i = tid; i < NBUK; i += 512) h[i] = 0;
    __syncthreads();
    int base = blockIdx.x * EPB;
#pragma unroll
    for (int it = 0; it < EPB / 512; it++) {
        int e = base + it * 512 + tid;
        if (e < NE) atomicAdd(&h[dst[e] >> 8], 1);
    }
    __syncthreads();
    for (int i = tid; i < NBUK; i += 512) hist[i * NBLK + blockIdx.x] = h[i];
}

// Pass 2a/2b/2c: exclusive scan of hist[HN] (bucket-major) -> bkoff[HN]
__global__ __launch_bounds__(256) void sum_tiles_kernel(const int* __restrict__ in,
                                                        int* __restrict__ tsum, int n) {
    int i = blockIdx.x * 256 + threadIdx.x;
    __shared__ int s[256];
    s[threadIdx.x] = (i < n) ? in[i] : 0;
    __syncthreads();
    for (int off = 128; off > 0; off >>= 1) {
        if (threadIdx.x < off) s[threadIdx.x] += s[threadIdx.x + off];
        __syncthreads();
    }
    if (threadIdx.x == 0) tsum[blockIdx.x] = s[0];
}

__global__ __launch_bounds__(256) void scan_tiles_kernel(const int* __restrict__ tsum,
                                                         int* __restrict__ toff, int ntiles) {
    int t = threadIdx.x;
    __shared__ int s[256];
    int v = (t < ntiles) ? tsum[t] : 0;
    s[t] = v;
    __syncthreads();
    for (int off = 1; off < 256; off <<= 1) {
        int u = (t >= off) ? s[t - off] : 0;
        __syncthreads();
        s[t] += u;
        __syncthreads();
    }
    if (t < ntiles) toff[t] = s[t] - v;
}

__global__ __launch_bounds__(256) void scan_out_kernel(const int* __restrict__ in,
                                                       const int* __restrict__ toff,
                                                       int* __restrict__ out, int n) {
    int i = blockIdx.x * 256 + threadIdx.x;
    int t = threadIdx.x;
    int v = (i < n) ? in[i] : 0;
    __shared__ int s[256];
    s[t] = v;
    __syncthreads();
    for (int off = 1; off < 256; off <<= 1) {
        int u = (t >= off) ? s[t - off] : 0;
        __syncthreads();
        s[t] += u;
        __syncthreads();
    }
    if (i < n) out[i] = toff[blockIdx.x] + s[t] - v;
}

// Pass 3: scatter edges into bucket-sorted ebuf, PACKED: (src<<8)|(dst&255).
__global__ __launch_bounds__(512) void bscatter_kernel(const int* __restrict__ src,
                                                       const int* __restrict__ dst,
                                                       const int* __restrict__ bkoff,
                                                       int* __restrict__ ebuf) {
    __shared__ int h[NBUK];
    int tid = threadIdx.x;
    for (int i = tid; i < NBUK; i += 512) h[i] = 0;
    __syncthreads();
    int base = blockIdx.x * EPB;
#pragma unroll
    for (int it = 0; it < EPB / 512; it++) {
        int e = base + it * 512 + tid;
        if (e < NE) {
            int d = dst[e];
            int bu = d >> 8;
            int p = atomicAdd(&h[bu], 1);
            ebuf[bkoff[bu * NBLK + blockIdx.x] + p] = (src[e] << 8) | (d & 255);
        }
    }
}

// Pass 4: one block per bucket: LDS histogram over dst&255 -> LDS scan
// -> rowptr for this bucket's nodes + scatter src into final CSR col.
__global__ __launch_bounds__(256) void bucket_csr_kernel(const int* __restrict__ ebuf,
                                                         const int* __restrict__ bkoff,
                                                         int* __restrict__ rowptr,
                                                         int* __restrict__ col) {
    __shared__ int cnt[256], exc[256], c2[256];
    int b = blockIdx.x, tid = threadIdx.x;
    int segstart = bkoff[b * NBLK];
    int segend = (b < NBUK - 1) ? bkoff[(b + 1) * NBLK] : NE;
    cnt[tid] = 0;
    c2[tid] = 0;
    __syncthreads();
    for (int i = segstart + tid; i < segend; i += 256)
        atomicAdd(&cnt[ebuf[i] & 255], 1);
    __syncthreads();
    int v = cnt[tid];
    exc[tid] = v;
    __syncthreads();
    for (int off = 1; off < 256; off <<= 1) {
        int u = (tid >= off) ? exc[tid - off] : 0;
        __syncthreads();
        exc[tid] += u;
        __syncthreads();
    }
    int excl = exc[tid] - v;  // exclusive prefix
    exc[tid] = excl;          // own-slot rewrite; others read only after barrier
    int node = (b << 8) + tid;
    if (node <= NN) rowptr[node] = segstart + excl;
    __syncthreads();
    for (int i = segstart + tid; i < segend; i += 256) {
        int ev = ebuf[i];
        int low = ev & 255;
        int p = atomicAdd(&c2[low], 1);
        col[segstart + exc[low] + p] = ((unsigned)ev) >> 8;
    }
}

// ---------- weight prep: fp32 [l][k][n] -> bf16 transposed [l][n][k] ----------
__global__ __launch_bounds__(256) void prep_kernel(const float* __restrict__ Ws1,
                                                   const float* __restrict__ Ws2,
                                                   unsigned short* __restrict__ W1T,
                                                   unsigned short* __restrict__ W2T) {
    int idx = blockIdx.x * 256 + threadIdx.x;  // [0, NL*DD*DD)
    int l = idx >> 14;
    int rem = idx & 16383;
    int k = rem >> 7;
    int n = rem & 127;
    int o = (l << 14) + (n << 7) + k;
    W1T[o] = f2bf(Ws1[idx]);
    W2T[o] = f2bf(Ws2[idx]);
}

// ---------- aggregation: hpre[i] = x[i] + sum_{j in N(i)} x[j], bf16 in/out ----------
// Standalone (NOT fused — R5: fusing cost 2.4x fetch rate via occupancy).
// 16 lanes/node, uint4 (8 bf16) per lane; fp32 accum; x8 edge unroll.
__global__ __launch_bounds__(256) void agg_kernel(const unsigned short* __restrict__ xbf,
                                                  const int* __restrict__ rowptr,
                                                  const int* __restrict__ col,
                                                  unsigned short* __restrict__ hpre) {
    int g = threadIdx.x >> 4;   // 16 node-groups per block
    int lane = threadIdx.x & 15;
    int node = blockIdx.x * 16 + g;  // NN = 3125*16 exactly
    const uint4* base = (const uint4*)xbf;
    float a[8];
    {
        uint4 v = base[node * 16 + lane];
        a[0] = __uint_as_float(v.x << 16); a[1] = __uint_as_float(v.x & 0xFFFF0000u);
        a[2] = __uint_as_float(v.y << 16); a[3] = __uint_as_float(v.y & 0xFFFF0000u);
        a[4] = __uint_as_float(v.z << 16); a[5] = __uint_as_float(v.z & 0xFFFF0000u);
        a[6] = __uint_as_float(v.w << 16); a[7] = __uint_as_float(v.w & 0xFFFF0000u);
    }
    int s = rowptr[node], e = rowptr[node + 1];
    int i = s;
    for (; i + 8 <= e; i += 8) {
        uint4 v0 = base[col[i] * 16 + lane];
        uint4 v1 = base[col[i + 1] * 16 + lane];
        uint4 v2 = base[col[i + 2] * 16 + lane];
        uint4 v3 = base[col[i + 3] * 16 + lane];
        uint4 v4 = base[col[i + 4] * 16 + lane];
        uint4 v5 = base[col[i + 5] * 16 + lane];
        uint4 v6 = base[col[i + 6] * 16 + lane];
        uint4 v7 = base[col[i + 7] * 16 + lane];
#define ACC(V)                                                            \
        a[0] += __uint_as_float(V.x << 16); a[1] += __uint_as_float(V.x & 0xFFFF0000u); \
        a[2] += __uint_as_float(V.y << 16); a[3] += __uint_as_float(V.y & 0xFFFF0000u); \
        a[4] += __uint_as_float(V.z << 16); a[5] += __uint_as_float(V.z & 0xFFFF0000u); \
        a[6] += __uint_as_float(V.w << 16); a[7] += __uint_as_float(V.w & 0xFFFF0000u)
        ACC(v0); ACC(v1); ACC(v2); ACC(v3); ACC(v4); ACC(v5); ACC(v6); ACC(v7);
    }
    for (; i < e; i++) {
        uint4 v = base[col[i] * 16 + lane];
        ACC(v);
    }
#undef ACC
    uint4 o;
    o.x = (unsigned int)f2bf(a[0]) | ((unsigned int)f2bf(a[1]) << 16);
    o.y = (unsigned int)f2bf(a[2]) | ((unsigned int)f2bf(a[3]) << 16);
    o.z = (unsigned int)f2bf(a[4]) | ((unsigned int)f2bf(a[5]) << 16);
    o.w = (unsigned int)f2bf(a[6]) | ((unsigned int)f2bf(a[7]) << 16);
    ((uint4*)hpre)[node * 16 + lane] = o;
}

// ---------- GEMM: O = [relu](A@WT^T + bias), 128 rows x 64 cols per block ----------
// R9: per-lane W loads from global = 16 cache lines/instr -> L1-request bound.
// Fix: stage the 16 KB W-half in LDS once per block (coalesced uint4), fragments
// via ds_read_b128; 2 m-tiles per wave so each B-frag feeds 2 MFMAs.
// R10 BUG (NaN): staging unpacked 8 uint4/row; a 128-short row is 16 uint4.
// n = idx>>4, kc = idx&15 — fixed.
#define WS_STR 136
template <bool RELU>
__global__ __launch_bounds__(256) void gemm_kernel(const unsigned short* __restrict__ A,
                                                   const unsigned short* __restrict__ WT,
                                                   const float* __restrict__ bias,
                                                   unsigned short* __restrict__ O) {
    __shared__ unsigned short Ws[64 * WS_STR];
    int bx = blockIdx.x;
    int m = bx >> 1, nh = bx & 1;
    int tid = threadIdx.x;

    // stage W-half: rows [nh*64, nh*64+64) of WT ([n][k], 256 B = 16 uint4 each)
    const uint4* wg = (const uint4*)(WT + (size_t)(nh * 64) * DD);  // 1024 uint4
#pragma unroll
    for (int it = 0; it < 4; it++) {
        int idx = it * 256 + tid;
        int n = idx >> 4, kc = idx & 15;
        *(uint4*)&Ws[n * WS_STR + kc * 8] = wg[idx];
    }
    __syncthreads();

    int w = tid >> 6;
    int lane = tid & 63;
    int quad = lane >> 4;
    int li = lane & 15;
    int rowb = m * 128 + w * 32;

    floatx4 acc[2][4];
#pragma unroll
    for (int mi = 0; mi < 2; mi++)
#pragma unroll
        for (int tn = 0; tn < 4; tn++) acc[mi][tn] = (floatx4){0.f, 0.f, 0.f, 0.f};

#pragma unroll
    for (int kk = 0; kk < 4; kk++) {
        int k0 = kk * 32 + quad * 8;
        short8 af[2];
#pragma unroll
        for (int mi = 0; mi < 2; mi++) {
            int ar = rowb + mi * 16 + li;
            af[mi] = (ar < NN) ? *(const short8*)(A + (size_t)ar * DD + k0)
                               : (short8){0, 0, 0, 0, 0, 0, 0, 0};
        }
#pragma unroll
        for (int tn = 0; tn < 4; tn++) {
            short8 bf = *(const short8*)&Ws[(tn * 16 + li) * WS_STR + k0];
            acc[0][tn] = __builtin_amdgcn_mfma_f32_16x16x32_bf16(af[0], bf, acc[0][tn], 0, 0, 0);
            acc[1][tn] = __builtin_amdgcn_mfma_f32_16x16x32_bf16(af[1], bf, acc[1][tn], 0, 0, 0);
        }
    }
#pragma unroll
    for (int tn = 0; tn < 4; tn++) {
        int colg = nh * 64 + tn * 16 + li;
        float bv = bias[colg];
#pragma unroll
        for (int mi = 0; mi < 2; mi++) {
#pragma unroll
            for (int r = 0; r < 4; r++) {
                int grow = rowb + mi * 16 + quad * 4 + r;
                if (grow < NN) {
                    float v = acc[mi][tn][r] + bv;
                    if (RELU) v = fmaxf(v, 0.f);
                    O[(size_t)grow * DD + colg] = f2bf(v);
                }
            }
        }
    }
}

// ---------- global add pool: batch sorted -> per-graph contiguous range ----------
__global__ __launch_bounds__(128) void pool_kernel(const unsigned short* __restrict__ x,
                                                   const int* __restrict__ batch,
                                                   float* __restrict__ out) {
    int g = blockIdx.x;
    int lo = 0, hi = NN;
    while (lo < hi) { int mid = (lo + hi) >> 1; if (batch[mid] < g) lo = mid + 1; else hi = mid; }
    int s = lo;
    hi = NN;
    while (lo < hi) { int mid = (lo + hi) >> 1; if (batch[mid] < g + 1) lo = mid + 1; else hi = mid; }
    int e = lo;
    int d = threadIdx.x;
    float acc = 0.f;
    for (int i = s; i < e; i++) acc += bf2f(x[(size_t)i * DD + d]);
    out[g * DD + d] = acc;
}

extern "C" void kernel_launch(void* const* d_in, const int* in_sizes, int n_in,
                              void* d_out, int out_size, void* d_ws, size_t ws_size,
                              hipStream_t stream) {
    const float* x0 = (const float*)d_in[0];
    const int* edge = (const int*)d_in[1];
    const int* batch = (const int*)d_in[2];
    const float* Ws1 = (const float*)d_in[3];
    const float* bs1 = (const float*)d_in[4];
    const float* Ws2 = (const float*)d_in[5];
    const float* bs2 = (const float*)d_in[6];
    float* out = (float*)d_out;
    const int* src = edge;
    const int* dst = edge + NE;

    char* ws = (char*)d_ws;
    size_t off = 0;
    auto alloc = [&](size_t bytes) {
        void* p = ws + off;
        off += (bytes + 255) & ~(size_t)255;
        return p;
    };
    unsigned short* x0bf = (unsigned short*)alloc((size_t)NN * DD * 2);
    unsigned short* xA = (unsigned short*)alloc((size_t)NN * DD * 2);
    unsigned short* xB = (unsigned short*)alloc((size_t)NN * DD * 2);
    unsigned short* hpre = (unsigned short*)alloc((size_t)NN * DD * 2);
    unsigned short* Hbuf = (unsigned short*)alloc((size_t)NN * DD * 2);
    int* col = (int*)alloc((size_t)NE * 4);
    int* ebuf = (int*)alloc((size_t)NE * 4);
    int* hist = (int*)alloc((size_t)HN * 4);
    int* bkoff = (int*)alloc((size_t)HN * 4);
    int* tsum = (int*)alloc((size_t)HT * 4);
    int* toff = (int*)alloc((size_t)HT * 4);
    int* rowptr = (int*)alloc((size_t)(NN + 1) * 4);
    unsigned short* W1T = (unsigned short*)alloc((size_t)NL * DD * DD * 2);
    unsigned short* W2T = (unsigned short*)alloc((size_t)NL * DD * DD * 2);

    cvt_kernel<<<(NN * DD / 4) / 256, 256, 0, stream>>>(x0, x0bf);
    bhist_kernel<<<NBLK, 512, 0, stream>>>(dst, hist);
    sum_tiles_kernel<<<HT, 256, 0, stream>>>(hist, tsum, HN);
    scan_tiles_kernel<<<1, 256, 0, stream>>>(tsum, toff, HT);
    scan_out_kernel<<<HT, 256, 0, stream>>>(hist, toff, bkoff, HN);
    bscatter_kernel<<<NBLK, 512, 0, stream>>>(src, dst, bkoff, ebuf);
    bucket_csr_kernel<<<NBUK, 256, 0, stream>>>(ebuf, bkoff, rowptr, col);
    prep_kernel<<<(NL * DD * DD) / 256, 256, 0, stream>>>(Ws1, Ws2, W1T, W2T);

    const unsigned short* xin = x0bf;
    unsigned short* bufs[2] = {xA, xB};
    const int gemm_grid = ((NN + 127) / 128) * 2;  // 782
    for (int l = 0; l < NL; l++) {
        agg_kernel<<<NN / 16, 256, 0, stream>>>(xin, rowptr, col, hpre);
        unsigned short* xout = bufs[l & 1];
        gemm_kernel<true><<<gemm_grid, 256, 0, stream>>>(hpre, W1T + l * DD * DD,
                                                         bs1 + l * DD, Hbuf);
        gemm_kernel<false><<<gemm_grid, 256, 0, stream>>>(Hbuf, W2T + l * DD * DD,
                                                          bs2 + l * DD, xout);
        xin = xout;
    }
    pool_kernel<<<NG, 128, 0, stream>>>(xin, batch, out);
}